// Round 8
// baseline (192.050 us; speedup 1.0000x reference)
//
#include <hip/hip_runtime.h>
#include <math.h>

// ---------------------------------------------------------------------------
// multi_head_attention: B=2, S=2048, D=1024, H=16, Hd=64, fp32 in/out.
// R17: qkv_gemm rebuilt as 256^2-tile, 8-wave, BK=32, 4-deep counted-vmcnt
//      GEMM (T3/T4-style: ONE non-draining WAITBAR(4) per K-tile, stage t+2
//      issued AFTER the barrier -> airtight buffer liveness {t,t+1} vs t+2).
//      Replaces the R6 m97-structure (vmcnt0-drain every K-step, ~20%
//      structural stall per m97 analysis). LDS 128KB static, 192 blocks of
//      512thr (1/CU). Same proven LDS swizzle + gemm_stage (unchanged, its
//      flat math covers 8 waves x 256 rows). Epilogues = mechanical
//      re-indexing of proven ones (V slot-permutation copied exactly).
//      attn = R16 (43.6us best); out/prep untouched for attribution.
// ---------------------------------------------------------------------------

using bf16   = __bf16;
using bf16x8 = __attribute__((ext_vector_type(8))) __bf16;
using bf16x4 = __attribute__((ext_vector_type(4))) __bf16;
using f32x4  = __attribute__((ext_vector_type(4))) float;

#define MFMA16(a, b, c) __builtin_amdgcn_mfma_f32_16x16x32_bf16((a), (b), (c), 0, 0, 0)
#define WAIT_VM0() asm volatile("s_waitcnt vmcnt(0)" ::: "memory")
#define WAITBAR(N) asm volatile("s_waitcnt vmcnt(" #N ")\n\ts_barrier" ::: "memory")

__device__ __forceinline__ bf16x8 ld8(const bf16* p) { return *(const bf16x8*)p; }

// async global->LDS, 16B/lane; lds_base is wave-uniform, HW adds lane*16.
__device__ __forceinline__ void ldg_lds16(bf16* lds_base, const bf16* g) {
    __builtin_amdgcn_global_load_lds(
        (const __attribute__((address_space(1))) void*)g,
        (__attribute__((address_space(3))) void*)lds_base, 16, 0, 0);
}

__device__ __forceinline__ float fast_exp2(float x) {
#if __has_builtin(__builtin_amdgcn_exp2f)
    return __builtin_amdgcn_exp2f(x);
#else
    return exp2f(x);
#endif
}

// ---------------------------------------------------------------------------
// Merged prep: z=0..3 transpose+convert W*; z=4 convert x -> bf16.
// ---------------------------------------------------------------------------
__global__ __launch_bounds__(256) void prep_kernel(
    const float* __restrict__ x, const float* __restrict__ Wq,
    const float* __restrict__ Wk, const float* __restrict__ Wv,
    const float* __restrict__ Wo, bf16* __restrict__ xb,
    bf16* __restrict__ WtBase) {
    const int z = blockIdx.z;
    const int tid = threadIdx.x;
    if (z == 4) {
        int id = blockIdx.y * 32 + blockIdx.x;      // 0..1023
#pragma unroll
        for (int k = 0; k < 4; ++k) {
            int i = id * 4096 + k * 1024 + tid * 4;
            float4 v = *(const float4*)&x[i];
            bf16x4 o = { (bf16)v.x, (bf16)v.y, (bf16)v.z, (bf16)v.w };
            *(bf16x4*)&xb[i] = o;
        }
        return;
    }
    __shared__ float tile[32][33];
    const float* W = (z == 0) ? Wq : (z == 1) ? Wk : (z == 2) ? Wv : Wo;
    bf16* Wt = WtBase + (size_t)z * 1024 * 1024;
    const int tx = tid & 31, ty = tid >> 5;          // 32 x 8
    const int x0 = blockIdx.x * 32, y0 = blockIdx.y * 32;
#pragma unroll
    for (int i = 0; i < 4; ++i)
        tile[ty + i * 8][tx] = W[(size_t)(y0 + ty + i * 8) * 1024 + x0 + tx];
    __syncthreads();
#pragma unroll
    for (int i = 0; i < 4; ++i)
        Wt[(size_t)(x0 + ty + i * 8) * 1024 + y0 + tx] = (bf16)tile[tx][ty + i * 8];
}

// ---------------------------------------------------------------------------
// Staging helper: w in 0..7 covers 256 rows x 32 k (one 16KB tile) with the
// proven (cc ^ ((row>>1)&3)) k-group swizzle; 2 ldg_lds/thread.
// (w in 0..3 covers 128 rows -- used by out_gemm's B staging.)
// ---------------------------------------------------------------------------
__device__ __forceinline__ void gemm_stage(const bf16* __restrict__ src, int r0,
                                           int k0, bf16* dst, int w, int lane) {
#pragma unroll
    for (int c = 0; c < 2; ++c) {
        int flat = (w * 2 + c) * 64 + lane;
        int row = flat >> 2, cc = flat & 3;
        int gk = (cc ^ ((row >> 1) & 3)) * 8;
        ldg_lds16(dst + (size_t)(w * 2 + c) * 512,
                  src + (size_t)(r0 + row) * 1024 + k0 + gk);
    }
}

// ---------------------------------------------------------------------------
// Fused QKV projection, 256x256 tiles, 8 waves, 4-deep counted-vmcnt pipeline.
// z=0 -> Q (scaled log2e/8), z=1 -> K, z=2 -> V transposed [B][H][Hd][S_perm]
// via LDS-transpose epilogue (4 x 64-row half-strips); key permutation
// slot = q4*8 + T16*4 + o <-> key = T16*16 + q4*4 + o folded into colp.
// Sync: loop = { WAITBAR(4|0) ; stage(t+2) ; ds_read + 32 MFMA }. Stage is
// issued AFTER the barrier -> all waves' reads of buf (t-1)&3 are complete
// (lgkmcnt before MFMA before barrier), writer buf (t+2)&3 disjoint from
// live readers {t, t+1}&3. vmcnt(4) leaves only t+1's 4 loads in flight.
// ---------------------------------------------------------------------------
__global__ __launch_bounds__(512, 2) void qkv_gemm_kernel(
    const bf16* __restrict__ Xb, const bf16* __restrict__ Wts,
    const float* __restrict__ bq, const float* __restrict__ bk,
    const float* __restrict__ bv,
    bf16* __restrict__ Qo, bf16* __restrict__ Ko, bf16* __restrict__ Vto) {
    __shared__ bf16 As[4 * 8192];     // 4 bufs x 256x32
    __shared__ bf16 Bs[4 * 8192];
    const int z = blockIdx.z;
    const bf16*  Bt   = Wts + (size_t)z * 1024 * 1024;
    const float* bias = (z == 0) ? bq : (z == 1) ? bk : bv;
    const int m0 = blockIdx.y * 256, n0 = blockIdx.x * 256;
    const int tid = threadIdx.x, lane = tid & 63, w = tid >> 6;
    const int lo = lane & 15, quad = lane >> 4;
    const int wm = w >> 2, wn = w & 3;            // 2 x 4 wave grid

    f32x4 acc[8][4] = {};

    gemm_stage(Xb, m0, 0, As, w, lane);           // tile 0
    gemm_stage(Bt, n0, 0, Bs, w, lane);
    gemm_stage(Xb, m0, 32, As + 8192, w, lane);   // tile 1
    gemm_stage(Bt, n0, 32, Bs + 8192, w, lane);

    int rbuf = 0, sbuf = 2;
    for (int it = 0; it < 32; ++it) {
        if (it < 31) { WAITBAR(4); } else { WAITBAR(0); }
        if (it + 2 < 32) {
            gemm_stage(Xb, m0, (it + 2) * 32, As + sbuf * 8192, w, lane);
            gemm_stage(Bt, n0, (it + 2) * 32, Bs + sbuf * 8192, w, lane);
            sbuf = (sbuf + 1) & 3;
        }
        const bf16* Ab = As + rbuf * 8192;
        const bf16* Bb = Bs + rbuf * 8192;
        bf16x8 af[8], bf[4];
#pragma unroll
        for (int t = 0; t < 8; ++t) {
            int r = wm * 128 + t * 16 + lo;
            af[t] = ld8(&Ab[r * 32 + ((quad ^ ((r >> 1) & 3)) * 8)]);
        }
#pragma unroll
        for (int t = 0; t < 4; ++t) {
            int r = wn * 64 + t * 16 + lo;
            bf[t] = ld8(&Bb[r * 32 + ((quad ^ ((r >> 1) & 3)) * 8)]);
        }
#pragma unroll
        for (int mt = 0; mt < 8; ++mt)
#pragma unroll
            for (int nt = 0; nt < 4; ++nt)
                acc[mt][nt] = MFMA16(af[mt], bf[nt], acc[mt][nt]);
        rbuf = (rbuf + 1) & 3;
    }

    const float QSCALE = 0.125f * 1.44269504088896f;  // 1/sqrt(64) * log2(e)

    if (z == 2) {
        // ---- V: 4 half-strips (256 n x 64 m), LDS transpose then permuted
        //      coalesced writes (formula identical to proven 128^2 version).
        bf16* T = As;                         // 256*68 = 17408 elems < 32768
        const int b = m0 >> 11;
        const int c0 = (m0 & 2047) >> 6;      // first 64-key chunk of tile
#pragma unroll
        for (int hm = 0; hm < 4; ++hm) {
            __syncthreads();
            if (wm == (hm >> 1)) {
                const int mfb = (hm & 1) * 4;
#pragma unroll
                for (int nt = 0; nt < 4; ++nt)
#pragma unroll
                    for (int mf = 0; mf < 4; ++mf)
#pragma unroll
                        for (int r = 0; r < 4; ++r) {
                            int nn = wn * 64 + nt * 16 + lo;
                            int mm = mf * 16 + quad * 4 + r;
                            T[nn * 68 + mm] =
                                (bf16)(acc[mfb + mf][nt][r] + bias[n0 + nn]);
                        }
            }
            __syncthreads();
            const int c = c0 + hm;
#pragma unroll
            for (int p = 0; p < 8; ++p) {
                int pos = p * 2048 + tid * 4;
                int row = pos >> 6, col = pos & 63;
                int n = n0 + row, h = n >> 6, hd = n & 63;
                int colp = (col & 32) | (((col >> 2) & 3) << 3)
                         | (((col >> 4) & 1) << 2) | (col & 3);
                bf16x4 v = *(const bf16x4*)&T[row * 68 + col];
                *(bf16x4*)&Vto[((size_t)((b * 16 + h) * 64 + hd) << 11)
                               + c * 64 + colp] = v;
            }
        }
    } else {
#pragma unroll
        for (int mt = 0; mt < 8; ++mt)
#pragma unroll
            for (int nt = 0; nt < 4; ++nt)
#pragma unroll
                for (int r = 0; r < 4; ++r) {
                    int m = m0 + wm * 128 + mt * 16 + quad * 4 + r;
                    int n = n0 + wn * 64 + nt * 16 + lo;
                    float v = acc[mt][nt][r] + bias[n];
                    int b = m >> 11, s = m & 2047, h = n >> 6, hd = n & 63;
                    if (z == 0)
                        Qo[((size_t)((b * 16 + h) * 2048 + s) << 6) + hd] = (bf16)(v * QSCALE);
                    else
                        Ko[((size_t)((b * 16 + h) * 2048 + s) << 6) + hd] = (bf16)v;
                }
    }
}

// ---------------------------------------------------------------------------
// Output projection, 64x128 tiles (512 blocks = 2/CU), double-buffered (R6).
// ---------------------------------------------------------------------------
__global__ __launch_bounds__(256, 2) void out_gemm_kernel(
    const bf16* __restrict__ A, const bf16* __restrict__ Bt,
    const float* __restrict__ bo, float* __restrict__ Co) {
    __shared__ bf16 As[2 * 2048];
    __shared__ bf16 Bs[2 * 4096];
    const int tid = threadIdx.x, lane = tid & 63, w = tid >> 6;
    const int lo = lane & 15, quad = lane >> 4;
    const int wm = w >> 1, wn = w & 1;
    const int m0 = blockIdx.y * 64, n0 = blockIdx.x * 128;

    auto stageA = [&](int k0, bf16* dst) {
        int flat = w * 64 + lane;
        int row = flat >> 2, cc = flat & 3;
        int gk = (cc ^ ((row >> 1) & 3)) * 8;
        ldg_lds16(dst + (size_t)w * 512, A + (size_t)(m0 + row) * 1024 + k0 + gk);
    };
    auto stageB = [&](int k0, bf16* dst) {
#pragma unroll
        for (int c = 0; c < 2; ++c) {
            int flat = (w * 2 + c) * 64 + lane;
            int row = flat >> 2, cc = flat & 3;
            int gk = (cc ^ ((row >> 1) & 3)) * 8;
            ldg_lds16(dst + (size_t)(w * 2 + c) * 512,
                      Bt + (size_t)(n0 + row) * 1024 + k0 + gk);
        }
    };

    f32x4 acc[2][4] = {};
    stageA(0, As);
    stageB(0, Bs);
    WAIT_VM0();
    __syncthreads();

    for (int it = 0; it < 32; ++it) {
        const int buf = it & 1;
        if (it + 1 < 32) {
            stageA((it + 1) * 32, As + (buf ^ 1) * 2048);
            stageB((it + 1) * 32, Bs + (buf ^ 1) * 4096);
        }
        const bf16* Ab = As + buf * 2048;
        const bf16* Bb = Bs + buf * 4096;
        bf16x8 af[2], bq[4];
#pragma unroll
        for (int t = 0; t < 2; ++t) {
            int r = wm * 32 + t * 16 + lo;
            af[t] = ld8(&Ab[r * 32 + ((quad ^ ((r >> 1) & 3)) * 8)]);
        }
#pragma unroll
        for (int t = 0; t < 4; ++t) {
            int r = wn * 64 + t * 16 + lo;
            bq[t] = ld8(&Bb[r * 32 + ((quad ^ ((r >> 1) & 3)) * 8)]);
        }
#pragma unroll
        for (int mt = 0; mt < 2; ++mt)
#pragma unroll
            for (int nt = 0; nt < 4; ++nt)
                acc[mt][nt] = MFMA16(af[mt], bq[nt], acc[mt][nt]);
        WAIT_VM0();
        __syncthreads();
    }

#pragma unroll
    for (int mt = 0; mt < 2; ++mt)
#pragma unroll
        for (int nt = 0; nt < 4; ++nt)
#pragma unroll
            for (int r = 0; r < 4; ++r) {
                int m = m0 + wm * 32 + mt * 16 + quad * 4 + r;
                int n = n0 + wn * 64 + nt * 16 + lo;
                Co[(size_t)m * 1024 + n] = acc[mt][nt][r] + bo[n];
            }
}

// ---------------------------------------------------------------------------
// Flash attention R16 (= R10 + hoisted-zero S init): software-pipelined S^T.
// Grid 512 x 256 (4 waves, 2 blk/CU). Block = 128 q-rows of one (b,h); each
// wave owns 32 q. 64-key chunks, K+V 4-deep LDS (64KB), staged 2 ahead,
// 4 ldg_lds/wave/chunk, counted WAITBAR(4). Per iteration (one region):
//   exp(S_i) [VALU] || S_{i+1}=K*Q^T [MFMA+LDS] || O+=P_i*V_i [MFMA+LDS]
// ---------------------------------------------------------------------------
__global__ __launch_bounds__(256, 2) void attn_kernel(
    const bf16* __restrict__ Q, const bf16* __restrict__ K,
    const bf16* __restrict__ Vt, bf16* __restrict__ AO) {
    __shared__ bf16 Ks[4][64 * 64];
    __shared__ bf16 Vs[4][64 * 64];
    const int tid = threadIdx.x, w = tid >> 6, lane = tid & 63;
    const int lo = lane & 15, quad = lane >> 4;
    const int blk = blockIdx.x;
    const int bh = (blk & 7) | ((blk >> 7) << 3);  // same-head -> same XCD
    const int qb = (blk >> 3) & 15;
    const int q0 = qb * 128 + w * 32;

    const bf16* Qb = Q + ((size_t)bh * 2048 + q0) * 64;
    const bf16* Kb = K + (size_t)bh * 2048 * 64;
    const bf16* Vb = Vt + (size_t)bh * 64 * 2048;

    // Q B-fragments: n-row = qt*16+lo, k = ks*32+quad*8
    bf16x8 qa[2][2];
#pragma unroll
    for (int qt = 0; qt < 2; ++qt)
#pragma unroll
        for (int ks = 0; ks < 2; ++ks)
            qa[qt][ks] = ld8(&Qb[(qt * 16 + lo) * 64 + ks * 32 + quad * 8]);

    f32x4 O[2][4] = {};
    float l_acc[2] = { 0.f, 0.f };
    const f32x4 ZERO = { 0.f, 0.f, 0.f, 0.f };   // hoisted C-operand

    // stage one 64-key K+V chunk (4 ldg_lds/wave); swizzle s(row)=row&7 both.
    auto stage = [&](int s0, int buf) {
#pragma unroll
        for (int c = 0; c < 2; ++c) {
            int flat = (w * 2 + c) * 64 + lane;
            int row = flat >> 3, cc = flat & 7;
            int g = (cc ^ (row & 7)) * 8;
            ldg_lds16(&Ks[buf][(w * 2 + c) * 512], &Kb[(size_t)(s0 + row) * 64 + g]);
            ldg_lds16(&Vs[buf][(w * 2 + c) * 512], &Vb[(size_t)row * 2048 + s0 + g]);
        }
    };

    const int swz = lo & 7;  // read-side swizzle for rows t*16+lo

    // ---- S^T = K * Q^T from Ks[nb] : 4 key m-tiles x 2 q n-tiles x 2 k ----
    auto qk = [&](int nb, f32x4 (&S)[2][4]) {
        const bf16* Kt = &Ks[nb][0];
#pragma unroll
        for (int t = 0; t < 4; ++t) {
            int r = t * 16 + lo;
            bf16x8 kf0 = ld8(&Kt[r * 64 + ((quad ^ swz) * 8)]);
            S[0][t] = MFMA16(kf0, qa[0][0], ZERO);
            S[1][t] = MFMA16(kf0, qa[1][0], ZERO);
            bf16x8 kf1 = ld8(&Kt[r * 64 + (((quad + 4) ^ swz) * 8)]);
            S[0][t] = MFMA16(kf1, qa[0][1], S[0][t]);
            S[1][t] = MFMA16(kf1, qa[1][1], S[1][t]);
        }
    };

    // ---- exp(Sin) -> pa (PV A-frags, keys slot-permuted) + l_acc ----
    auto expP = [&](f32x4 (&Sin)[2][4], bf16x8 (&pa)[2][2]) {
#pragma unroll
        for (int qt = 0; qt < 2; ++qt)
#pragma unroll
            for (int kc = 0; kc < 2; ++kc) {
                float e0 = fast_exp2(Sin[qt][2 * kc][0]);
                float e1 = fast_exp2(Sin[qt][2 * kc][1]);
                float e2 = fast_exp2(Sin[qt][2 * kc][2]);
                float e3 = fast_exp2(Sin[qt][2 * kc][3]);
                float e4 = fast_exp2(Sin[qt][2 * kc + 1][0]);
                float e5 = fast_exp2(Sin[qt][2 * kc + 1][1]);
                float e6 = fast_exp2(Sin[qt][2 * kc + 1][2]);
                float e7 = fast_exp2(Sin[qt][2 * kc + 1][3]);
                l_acc[qt] += ((e0 + e1) + (e2 + e3)) + ((e4 + e5) + (e6 + e7));
                pa[qt][kc] = bf16x8{ (bf16)e0, (bf16)e1, (bf16)e2, (bf16)e3,
                                     (bf16)e4, (bf16)e5, (bf16)e6, (bf16)e7 };
            }
    };

    // ---- PV from Vs[cb] ----
    auto pv = [&](int cb, bf16x8 (&pa)[2][2]) {
        const bf16* Vl = &Vs[cb][0];
#pragma unroll
        for (int kc = 0; kc < 2; ++kc)
#pragma unroll
            for (int nt = 0; nt < 4; ++nt) {
                int r = nt * 16 + lo;
                bf16x8 vf = ld8(&Vl[r * 64 + ((((kc * 4 + quad) ^ swz)) * 8)]);
                O[0][nt] = MFMA16(pa[0][kc], vf, O[0][nt]);
                O[1][nt] = MFMA16(pa[1][kc], vf, O[1][nt]);
            }
    };

    // step i: exp(S_i) || S_{i+1}=qk || O+=P_i*V_i  (one region, no barrier)
    auto step = [&](f32x4 (&Sin)[2][4], f32x4 (&Sout)[2][4], int cb, int nb) {
        bf16x8 pa[2][2];
        expP(Sin, pa);
        qk(nb, Sout);
        pv(cb, pa);
    };

    stage(0, 0);
    stage(64, 1);
    WAITBAR(4);                     // chunk0 ready; chunk1 in flight

    f32x4 Sa[2][4], Sb[2][4];
    qk(0, Sa);

    for (int it = 0; it < 30; it += 2) {
        stage((it + 2) * 64, (it + 2) & 3);
        WAITBAR(4);                 // chunk it+1 ready
        step(Sa, Sb, it & 3, (it + 1) & 3);
        stage((it + 3) * 64, (it + 3) & 3);
        WAITBAR(4);                 // chunk it+2 ready
        step(Sb, Sa, (it + 1) & 3, (it + 2) & 3);
    }
    WAITBAR(0);                     // chunk 31 ready
    step(Sa, Sb, 2, 3);             // exp(S30) || qk(31) || PV(30)
    {                               // tail: exp(S31) + PV(31)
        bf16x8 pa[2][2];
        expP(Sb, pa);
        pv(3, pa);
    }

    // ---- epilogue: l lives at q=lo; redistribute to C-rows via shfl ----
    const int bb = bh >> 4, h = bh & 15;
#pragma unroll
    for (int qt = 0; qt < 2; ++qt) {
        float lt = l_acc[qt];
        lt += __shfl_xor(lt, 16, 64);
        lt += __shfl_xor(lt, 32, 64);   // total l for q = qt*16 + lo
        const size_t outbase = ((size_t)(bb * 2048 + q0 + qt * 16)) * 1024 + h * 64;
#pragma unroll
        for (int r = 0; r < 4; ++r) {
            float rl = 1.0f / __shfl(lt, quad * 4 + r, 64);
            size_t rowoff = outbase + (size_t)(quad * 4 + r) * 1024;
#pragma unroll
            for (int nt = 0; nt < 4; ++nt)
                AO[rowoff + nt * 16 + lo] = (bf16)(O[qt][nt][r] * rl);
        }
    }
}

// ---------------------------------------------------------------------------
extern "C" void kernel_launch(void* const* d_in, const int* in_sizes, int n_in,
                              void* d_out, int out_size, void* d_ws, size_t ws_size,
                              hipStream_t stream) {
    const float* x  = (const float*)d_in[0];
    const float* Wq = (const float*)d_in[1];
    const float* bq = (const float*)d_in[2];
    const float* Wk = (const float*)d_in[3];
    const float* bk = (const float*)d_in[4];
    const float* Wv = (const float*)d_in[5];
    const float* bv = (const float*)d_in[6];
    const float* Wo = (const float*)d_in[7];
    const float* bo = (const float*)d_in[8];
    float* out = (float*)d_out;

    bf16* wsb = (bf16*)d_ws;
    const size_t M1 = 1024u * 1024u;
    bf16* Xb  = wsb;
    bf16* AO  = wsb;            // aliases Xb (Xb dead after qkv_gemm)
    bf16* Wt  = wsb + 4 * M1;
    bf16* Qw  = wsb + 8 * M1;
    bf16* Kw  = wsb + 12 * M1;
    bf16* Vtw = wsb + 16 * M1;

    prep_kernel<<<dim3(32, 32, 5), 256, 0, stream>>>(x, Wq, Wk, Wv, Wo, Xb, Wt);
    qkv_gemm_kernel<<<dim3(4, 16, 3), 512, 0, stream>>>(Xb, Wt, bq, bk, bv, Qw, Kw, Vtw);
    attn_kernel<<<512, 256, 0, stream>>>(Qw, Kw, Vtw, AO);
    out_gemm_kernel<<<dim3(8, 64), 256, 0, stream>>>(AO, Wt + 3 * M1, bo, out);
}

// Round 9
// 183.605 us; speedup vs baseline: 1.0460x; 1.0460x over previous
//
#include <hip/hip_runtime.h>
#include <math.h>

// ---------------------------------------------------------------------------
// multi_head_attention: B=2, S=2048, D=1024, H=16, Hd=64, fp32 in/out.
// R18 = exact revert to R16 (session best, 179.7us). R17's 256^2 qkv regressed
//      2x: 256^2 tile in a 2-barrier coarse loop is structure-mismatched
//      (m103/m105: 792 vs 912 TF) AND 128KB LDS -> 1 blk/CU killed the
//      inter-block TLP (m114) that hides the m97 barrier drain. Lesson
//      (3rd occurrence): TLP > pipeline depth in 2-barrier structures.
// R16: attn = R10 structure + hoisted-zero S init (43.6us; seven structural
//      variants R9-R15 all 43-47, MfmaUtil pinned ~29 -- parked). GEMMs = R6
//      128^2 m97-structure at its ~870 TF ceiling (structure-matched).
//      Budget: attn 43.6 + qkv ~30 + out ~10 + prep ~5 + ~87.6 harness
//      re-poison (uncontrollable).
// ---------------------------------------------------------------------------

using bf16   = __bf16;
using bf16x8 = __attribute__((ext_vector_type(8))) __bf16;
using bf16x4 = __attribute__((ext_vector_type(4))) __bf16;
using f32x4  = __attribute__((ext_vector_type(4))) float;

#define MFMA16(a, b, c) __builtin_amdgcn_mfma_f32_16x16x32_bf16((a), (b), (c), 0, 0, 0)
#define WAIT_VM0() asm volatile("s_waitcnt vmcnt(0)" ::: "memory")
#define WAITBAR(N) asm volatile("s_waitcnt vmcnt(" #N ")\n\ts_barrier" ::: "memory")

__device__ __forceinline__ bf16x8 ld8(const bf16* p) { return *(const bf16x8*)p; }

// async global->LDS, 16B/lane; lds_base is wave-uniform, HW adds lane*16.
__device__ __forceinline__ void ldg_lds16(bf16* lds_base, const bf16* g) {
    __builtin_amdgcn_global_load_lds(
        (const __attribute__((address_space(1))) void*)g,
        (__attribute__((address_space(3))) void*)lds_base, 16, 0, 0);
}

__device__ __forceinline__ float fast_exp2(float x) {
#if __has_builtin(__builtin_amdgcn_exp2f)
    return __builtin_amdgcn_exp2f(x);
#else
    return exp2f(x);
#endif
}

// ---------------------------------------------------------------------------
// Merged prep: z=0..3 transpose+convert W*; z=4 convert x -> bf16.
// ---------------------------------------------------------------------------
__global__ __launch_bounds__(256) void prep_kernel(
    const float* __restrict__ x, const float* __restrict__ Wq,
    const float* __restrict__ Wk, const float* __restrict__ Wv,
    const float* __restrict__ Wo, bf16* __restrict__ xb,
    bf16* __restrict__ WtBase) {
    const int z = blockIdx.z;
    const int tid = threadIdx.x;
    if (z == 4) {
        int id = blockIdx.y * 32 + blockIdx.x;      // 0..1023
#pragma unroll
        for (int k = 0; k < 4; ++k) {
            int i = id * 4096 + k * 1024 + tid * 4;
            float4 v = *(const float4*)&x[i];
            bf16x4 o = { (bf16)v.x, (bf16)v.y, (bf16)v.z, (bf16)v.w };
            *(bf16x4*)&xb[i] = o;
        }
        return;
    }
    __shared__ float tile[32][33];
    const float* W = (z == 0) ? Wq : (z == 1) ? Wk : (z == 2) ? Wv : Wo;
    bf16* Wt = WtBase + (size_t)z * 1024 * 1024;
    const int tx = tid & 31, ty = tid >> 5;          // 32 x 8
    const int x0 = blockIdx.x * 32, y0 = blockIdx.y * 32;
#pragma unroll
    for (int i = 0; i < 4; ++i)
        tile[ty + i * 8][tx] = W[(size_t)(y0 + ty + i * 8) * 1024 + x0 + tx];
    __syncthreads();
#pragma unroll
    for (int i = 0; i < 4; ++i)
        Wt[(size_t)(x0 + ty + i * 8) * 1024 + y0 + tx] = (bf16)tile[tx][ty + i * 8];
}

// ---------------------------------------------------------------------------
// 128x128 GEMM core, async double-buffered (R6 exact).
// ---------------------------------------------------------------------------
__device__ __forceinline__ void gemm_stage(const bf16* __restrict__ src, int r0,
                                           int k0, bf16* dst, int w, int lane) {
#pragma unroll
    for (int c = 0; c < 2; ++c) {
        int flat = (w * 2 + c) * 64 + lane;
        int row = flat >> 2, cc = flat & 3;
        int gk = (cc ^ ((row >> 1) & 3)) * 8;
        ldg_lds16(dst + (size_t)(w * 2 + c) * 512,
                  src + (size_t)(r0 + row) * 1024 + k0 + gk);
    }
}

__device__ __forceinline__ void gemm_core_128(const bf16* __restrict__ A,
                                              const bf16* __restrict__ Bt,
                                              int m0, int n0,
                                              bf16* As, bf16* Bs,   // each 2*4096
                                              f32x4 (&acc)[4][4]) {
    const int tid = threadIdx.x, lane = tid & 63, w = tid >> 6;
    const int lo = lane & 15, quad = lane >> 4;
    const int wm = w >> 1, wn = w & 1;

    gemm_stage(A,  m0, 0, As, w, lane);
    gemm_stage(Bt, n0, 0, Bs, w, lane);
    WAIT_VM0();
    __syncthreads();

    for (int it = 0; it < 32; ++it) {
        const int buf = it & 1;
        if (it + 1 < 32) {
            gemm_stage(A,  m0, (it + 1) * 32, As + (buf ^ 1) * 4096, w, lane);
            gemm_stage(Bt, n0, (it + 1) * 32, Bs + (buf ^ 1) * 4096, w, lane);
        }
        const bf16* Ab = As + buf * 4096;
        const bf16* Bb = Bs + buf * 4096;
        bf16x8 af[4], bq[4];
#pragma unroll
        for (int t = 0; t < 4; ++t) {
            int r = wm * 64 + t * 16 + lo;
            af[t] = ld8(&Ab[r * 32 + ((quad ^ ((r >> 1) & 3)) * 8)]);
        }
#pragma unroll
        for (int t = 0; t < 4; ++t) {
            int r = wn * 64 + t * 16 + lo;
            bq[t] = ld8(&Bb[r * 32 + ((quad ^ ((r >> 1) & 3)) * 8)]);
        }
#pragma unroll
        for (int mt = 0; mt < 4; ++mt)
#pragma unroll
            for (int nt = 0; nt < 4; ++nt)
                acc[mt][nt] = MFMA16(af[mt], bq[nt], acc[mt][nt]);
        WAIT_VM0();
        __syncthreads();
    }
}

// Fused QKV projection. z=0 -> Q (scaled log2e/8), z=1 -> K, z=2 -> V
// transposed [B][H][Hd][S_perm] via LDS-transpose epilogue; the s coordinate
// is permuted within each 32-key group: col' keeps attn's PV slot mapping
// slot = quad*8 + T*4 + o  <->  key = T*16 + quad*4 + o.
__global__ __launch_bounds__(256, 3) void qkv_gemm_kernel(
    const bf16* __restrict__ Xb, const bf16* __restrict__ Wts,
    const float* __restrict__ bq, const float* __restrict__ bk,
    const float* __restrict__ bv,
    bf16* __restrict__ Qo, bf16* __restrict__ Ko, bf16* __restrict__ Vto) {
    __shared__ bf16 Smem[4 * 4096];
    bf16* As = Smem;
    bf16* Bs = Smem + 2 * 4096;
    const int z = blockIdx.z;
    const bf16*  Bt   = Wts + (size_t)z * 1024 * 1024;
    const float* bias = (z == 0) ? bq : (z == 1) ? bk : bv;
    const int m0 = blockIdx.y * 128, n0 = blockIdx.x * 128;

    f32x4 acc[4][4] = {};
    gemm_core_128(Xb, Bt, m0, n0, As, Bs, acc);

    const int tid = threadIdx.x;
    const int lane = tid & 63, w = tid >> 6;
    const int lo = lane & 15, quad = lane >> 4;
    const int wm = w >> 1, wn = w & 1;
    const float QSCALE = 0.125f * 1.44269504088896f;  // 1/sqrt(64) * log2(e)

    if (z == 2) {
        // ---- V: transpose via LDS (two 128n x 64m half-tiles, stride 68) ----
        bf16* T = Smem;                      // 128*68 = 8704 elems
        const int b = m0 >> 11;
        const int s_base = m0 & 2047;
#pragma unroll
        for (int half = 0; half < 2; ++half) {
            __syncthreads();
            if (wm == half) {
#pragma unroll
                for (int nt = 0; nt < 4; ++nt)
#pragma unroll
                    for (int mt = 0; mt < 4; ++mt)
#pragma unroll
                        for (int r = 0; r < 4; ++r) {
                            int nn = wn * 64 + nt * 16 + lo;
                            int mm = mt * 16 + quad * 4 + r;
                            T[nn * 68 + mm] = (bf16)(acc[mt][nt][r] + bias[n0 + nn]);
                        }
            }
            __syncthreads();
#pragma unroll
            for (int p = 0; p < 8; ++p) {
                int pos = p * 1024 + tid * 4;
                int row = pos >> 6, col = pos & 63;
                int n = n0 + row, h = n >> 6, hd = n & 63;
                // permute key within its 32-group: slot = q4*8 + T16*4 + o
                int colp = (col & 32) | (((col >> 2) & 3) << 3)
                         | (((col >> 4) & 1) << 2) | (col & 3);
                bf16x4 v = *(const bf16x4*)&T[row * 68 + col];
                *(bf16x4*)&Vto[((size_t)((b * 16 + h) * 64 + hd) << 11)
                               + s_base + half * 64 + colp] = v;
            }
        }
    } else {
#pragma unroll
        for (int mt = 0; mt < 4; ++mt)
#pragma unroll
            for (int nt = 0; nt < 4; ++nt)
#pragma unroll
                for (int r = 0; r < 4; ++r) {
                    int m = m0 + wm * 64 + mt * 16 + quad * 4 + r;
                    int n = n0 + wn * 64 + nt * 16 + lo;
                    float v = acc[mt][nt][r] + bias[n];
                    int b = m >> 11, s = m & 2047, h = n >> 6, hd = n & 63;
                    if (z == 0)
                        Qo[((size_t)((b * 16 + h) * 2048 + s) << 6) + hd] = (bf16)(v * QSCALE);
                    else
                        Ko[((size_t)((b * 16 + h) * 2048 + s) << 6) + hd] = (bf16)v;
                }
    }
}

// ---------------------------------------------------------------------------
// Output projection, 64x128 tiles (512 blocks = 2/CU), double-buffered (R6).
// ---------------------------------------------------------------------------
__global__ __launch_bounds__(256, 2) void out_gemm_kernel(
    const bf16* __restrict__ A, const bf16* __restrict__ Bt,
    const float* __restrict__ bo, float* __restrict__ Co) {
    __shared__ bf16 As[2 * 2048];
    __shared__ bf16 Bs[2 * 4096];
    const int tid = threadIdx.x, lane = tid & 63, w = tid >> 6;
    const int lo = lane & 15, quad = lane >> 4;
    const int wm = w >> 1, wn = w & 1;
    const int m0 = blockIdx.y * 64, n0 = blockIdx.x * 128;

    auto stageA = [&](int k0, bf16* dst) {
        int flat = w * 64 + lane;
        int row = flat >> 2, cc = flat & 3;
        int gk = (cc ^ ((row >> 1) & 3)) * 8;
        ldg_lds16(dst + (size_t)w * 512, A + (size_t)(m0 + row) * 1024 + k0 + gk);
    };
    auto stageB = [&](int k0, bf16* dst) {
#pragma unroll
        for (int c = 0; c < 2; ++c) {
            int flat = (w * 2 + c) * 64 + lane;
            int row = flat >> 2, cc = flat & 3;
            int gk = (cc ^ ((row >> 1) & 3)) * 8;
            ldg_lds16(dst + (size_t)(w * 2 + c) * 512,
                      Bt + (size_t)(n0 + row) * 1024 + k0 + gk);
        }
    };

    f32x4 acc[2][4] = {};
    stageA(0, As);
    stageB(0, Bs);
    WAIT_VM0();
    __syncthreads();

    for (int it = 0; it < 32; ++it) {
        const int buf = it & 1;
        if (it + 1 < 32) {
            stageA((it + 1) * 32, As + (buf ^ 1) * 2048);
            stageB((it + 1) * 32, Bs + (buf ^ 1) * 4096);
        }
        const bf16* Ab = As + buf * 2048;
        const bf16* Bb = Bs + buf * 4096;
        bf16x8 af[2], bq[4];
#pragma unroll
        for (int t = 0; t < 2; ++t) {
            int r = wm * 32 + t * 16 + lo;
            af[t] = ld8(&Ab[r * 32 + ((quad ^ ((r >> 1) & 3)) * 8)]);
        }
#pragma unroll
        for (int t = 0; t < 4; ++t) {
            int r = wn * 64 + t * 16 + lo;
            bq[t] = ld8(&Bb[r * 32 + ((quad ^ ((r >> 1) & 3)) * 8)]);
        }
#pragma unroll
        for (int mt = 0; mt < 2; ++mt)
#pragma unroll
            for (int nt = 0; nt < 4; ++nt)
                acc[mt][nt] = MFMA16(af[mt], bq[nt], acc[mt][nt]);
        WAIT_VM0();
        __syncthreads();
    }

#pragma unroll
    for (int mt = 0; mt < 2; ++mt)
#pragma unroll
        for (int nt = 0; nt < 4; ++nt)
#pragma unroll
            for (int r = 0; r < 4; ++r) {
                int m = m0 + wm * 32 + mt * 16 + quad * 4 + r;
                int n = n0 + wn * 64 + nt * 16 + lo;
                Co[(size_t)m * 1024 + n] = acc[mt][nt][r] + bo[n];
            }
}

// ---------------------------------------------------------------------------
// Flash attention R16 (= R10 + hoisted-zero S init): software-pipelined S^T.
// Grid 512 x 256 (4 waves, 2 blk/CU). Block = 128 q-rows of one (b,h); each
// wave owns 32 q. 64-key chunks, K+V 4-deep LDS (64KB), staged 2 ahead,
// 4 ldg_lds/wave/chunk, counted WAITBAR(4). Per iteration (one region):
//   exp(S_i) [VALU] || S_{i+1}=K*Q^T [MFMA+LDS] || O+=P_i*V_i [MFMA+LDS]
// ---------------------------------------------------------------------------
__global__ __launch_bounds__(256, 2) void attn_kernel(
    const bf16* __restrict__ Q, const bf16* __restrict__ K,
    const bf16* __restrict__ Vt, bf16* __restrict__ AO) {
    __shared__ bf16 Ks[4][64 * 64];
    __shared__ bf16 Vs[4][64 * 64];
    const int tid = threadIdx.x, w = tid >> 6, lane = tid & 63;
    const int lo = lane & 15, quad = lane >> 4;
    const int blk = blockIdx.x;
    const int bh = (blk & 7) | ((blk >> 7) << 3);  // same-head -> same XCD
    const int qb = (blk >> 3) & 15;
    const int q0 = qb * 128 + w * 32;

    const bf16* Qb = Q + ((size_t)bh * 2048 + q0) * 64;
    const bf16* Kb = K + (size_t)bh * 2048 * 64;
    const bf16* Vb = Vt + (size_t)bh * 64 * 2048;

    // Q B-fragments: n-row = qt*16+lo, k = ks*32+quad*8
    bf16x8 qa[2][2];
#pragma unroll
    for (int qt = 0; qt < 2; ++qt)
#pragma unroll
        for (int ks = 0; ks < 2; ++ks)
            qa[qt][ks] = ld8(&Qb[(qt * 16 + lo) * 64 + ks * 32 + quad * 8]);

    f32x4 O[2][4] = {};
    float l_acc[2] = { 0.f, 0.f };
    const f32x4 ZERO = { 0.f, 0.f, 0.f, 0.f };   // hoisted C-operand

    // stage one 64-key K+V chunk (4 ldg_lds/wave); swizzle s(row)=row&7 both.
    auto stage = [&](int s0, int buf) {
#pragma unroll
        for (int c = 0; c < 2; ++c) {
            int flat = (w * 2 + c) * 64 + lane;
            int row = flat >> 3, cc = flat & 7;
            int g = (cc ^ (row & 7)) * 8;
            ldg_lds16(&Ks[buf][(w * 2 + c) * 512], &Kb[(size_t)(s0 + row) * 64 + g]);
            ldg_lds16(&Vs[buf][(w * 2 + c) * 512], &Vb[(size_t)row * 2048 + s0 + g]);
        }
    };

    const int swz = lo & 7;  // read-side swizzle for rows t*16+lo

    // ---- S^T = K * Q^T from Ks[nb] : 4 key m-tiles x 2 q n-tiles x 2 k ----
    auto qk = [&](int nb, f32x4 (&S)[2][4]) {
        const bf16* Kt = &Ks[nb][0];
#pragma unroll
        for (int t = 0; t < 4; ++t) {
            int r = t * 16 + lo;
            bf16x8 kf0 = ld8(&Kt[r * 64 + ((quad ^ swz) * 8)]);
            S[0][t] = MFMA16(kf0, qa[0][0], ZERO);
            S[1][t] = MFMA16(kf0, qa[1][0], ZERO);
            bf16x8 kf1 = ld8(&Kt[r * 64 + (((quad + 4) ^ swz) * 8)]);
            S[0][t] = MFMA16(kf1, qa[0][1], S[0][t]);
            S[1][t] = MFMA16(kf1, qa[1][1], S[1][t]);
        }
    };

    // ---- exp(Sin) -> pa (PV A-frags, keys slot-permuted) + l_acc ----
    auto expP = [&](f32x4 (&Sin)[2][4], bf16x8 (&pa)[2][2]) {
#pragma unroll
        for (int qt = 0; qt < 2; ++qt)
#pragma unroll
            for (int kc = 0; kc < 2; ++kc) {
                float e0 = fast_exp2(Sin[qt][2 * kc][0]);
                float e1 = fast_exp2(Sin[qt][2 * kc][1]);
                float e2 = fast_exp2(Sin[qt][2 * kc][2]);
                float e3 = fast_exp2(Sin[qt][2 * kc][3]);
                float e4 = fast_exp2(Sin[qt][2 * kc + 1][0]);
                float e5 = fast_exp2(Sin[qt][2 * kc + 1][1]);
                float e6 = fast_exp2(Sin[qt][2 * kc + 1][2]);
                float e7 = fast_exp2(Sin[qt][2 * kc + 1][3]);
                l_acc[qt] += ((e0 + e1) + (e2 + e3)) + ((e4 + e5) + (e6 + e7));
                pa[qt][kc] = bf16x8{ (bf16)e0, (bf16)e1, (bf16)e2, (bf16)e3,
                                     (bf16)e4, (bf16)e5, (bf16)e6, (bf16)e7 };
            }
    };

    // ---- PV from Vs[cb] ----
    auto pv = [&](int cb, bf16x8 (&pa)[2][2]) {
        const bf16* Vl = &Vs[cb][0];
#pragma unroll
        for (int kc = 0; kc < 2; ++kc)
#pragma unroll
            for (int nt = 0; nt < 4; ++nt) {
                int r = nt * 16 + lo;
                bf16x8 vf = ld8(&Vl[r * 64 + ((((kc * 4 + quad) ^ swz)) * 8)]);
                O[0][nt] = MFMA16(pa[0][kc], vf, O[0][nt]);
                O[1][nt] = MFMA16(pa[1][kc], vf, O[1][nt]);
            }
    };

    // step i: exp(S_i) || S_{i+1}=qk || O+=P_i*V_i  (one region, no barrier)
    auto step = [&](f32x4 (&Sin)[2][4], f32x4 (&Sout)[2][4], int cb, int nb) {
        bf16x8 pa[2][2];
        expP(Sin, pa);
        qk(nb, Sout);
        pv(cb, pa);
    };

    stage(0, 0);
    stage(64, 1);
    WAITBAR(4);                     // chunk0 ready; chunk1 in flight

    f32x4 Sa[2][4], Sb[2][4];
    qk(0, Sa);

    for (int it = 0; it < 30; it += 2) {
        stage((it + 2) * 64, (it + 2) & 3);
        WAITBAR(4);                 // chunk it+1 ready
        step(Sa, Sb, it & 3, (it + 1) & 3);
        stage((it + 3) * 64, (it + 3) & 3);
        WAITBAR(4);                 // chunk it+2 ready
        step(Sb, Sa, (it + 1) & 3, (it + 2) & 3);
    }
    WAITBAR(0);                     // chunk 31 ready
    step(Sa, Sb, 2, 3);             // exp(S30) || qk(31) || PV(30)
    {                               // tail: exp(S31) + PV(31)
        bf16x8 pa[2][2];
        expP(Sb, pa);
        pv(3, pa);
    }

    // ---- epilogue: l lives at q=lo; redistribute to C-rows via shfl ----
    const int bb = bh >> 4, h = bh & 15;
#pragma unroll
    for (int qt = 0; qt < 2; ++qt) {
        float lt = l_acc[qt];
        lt += __shfl_xor(lt, 16, 64);
        lt += __shfl_xor(lt, 32, 64);   // total l for q = qt*16 + lo
        const size_t outbase = ((size_t)(bb * 2048 + q0 + qt * 16)) * 1024 + h * 64;
#pragma unroll
        for (int r = 0; r < 4; ++r) {
            float rl = 1.0f / __shfl(lt, quad * 4 + r, 64);
            size_t rowoff = outbase + (size_t)(quad * 4 + r) * 1024;
#pragma unroll
            for (int nt = 0; nt < 4; ++nt)
                AO[rowoff + nt * 16 + lo] = (bf16)(O[qt][nt][r] * rl);
        }
    }
}

// ---------------------------------------------------------------------------
extern "C" void kernel_launch(void* const* d_in, const int* in_sizes, int n_in,
                              void* d_out, int out_size, void* d_ws, size_t ws_size,
                              hipStream_t stream) {
    const float* x  = (const float*)d_in[0];
    const float* Wq = (const float*)d_in[1];
    const float* bq = (const float*)d_in[2];
    const float* Wk = (const float*)d_in[3];
    const float* bk = (const float*)d_in[4];
    const float* Wv = (const float*)d_in[5];
    const float* bv = (const float*)d_in[6];
    const float* Wo = (const float*)d_in[7];
    const float* bo = (const float*)d_in[8];
    float* out = (float*)d_out;

    bf16* wsb = (bf16*)d_ws;
    const size_t M1 = 1024u * 1024u;
    bf16* Xb  = wsb;
    bf16* AO  = wsb;            // aliases Xb (Xb dead after qkv_gemm)
    bf16* Wt  = wsb + 4 * M1;
    bf16* Qw  = wsb + 8 * M1;
    bf16* Kw  = wsb + 12 * M1;
    bf16* Vtw = wsb + 16 * M1;

    prep_kernel<<<dim3(32, 32, 5), 256, 0, stream>>>(x, Wq, Wk, Wv, Wo, Xb, Wt);
    qkv_gemm_kernel<<<dim3(8, 32, 3), 256, 0, stream>>>(Xb, Wt, bq, bk, bv, Qw, Kw, Vtw);
    attn_kernel<<<512, 256, 0, stream>>>(Qw, Kw, Vtw, AO);
    out_gemm_kernel<<<dim3(8, 64), 256, 0, stream>>>(AO, Wt + 3 * M1, bo, out);
}

// Round 10
// 179.730 us; speedup vs baseline: 1.0685x; 1.0216x over previous
//
#include <hip/hip_runtime.h>
#include <math.h>

// ---------------------------------------------------------------------------
// multi_head_attention: B=2, S=2048, D=1024, H=16, Hd=64, fp32 in/out.
// R19 = R16/R18 verbatim (session best: 179.7us, re-measured 183.6 -- same
//      code, +-2% harness noise). Banked as the validated plateau:
//      - attn 43.6us: R10 structure (V-in-LDS, 4-wave, exp||qk||pv fused
//        region, 4-deep counted-vmcnt staging) + hoisted-zero S init.
//        Seven structural variants (R9-R15) all 43-47us, MfmaUtil pinned
//        ~29%; 2 waves/SIMD is geometry-forced (512 natural 128-q blocks).
//      - qkv ~30us / out ~10us: R6 128^2 m97-structure at its ~870TF
//        ceiling (structure-matched per m103; R17's 256^2 coarse-loop
//        attempt regressed 2x and was reverted).
//      - ~88us harness workspace re-poison is uncontrollable.
//      Next candidates (for a session with compile-iterate tooling):
//      faithful m201 8-phase qkv port; split-K attn + fused combine.
// ---------------------------------------------------------------------------

using bf16   = __bf16;
using bf16x8 = __attribute__((ext_vector_type(8))) __bf16;
using bf16x4 = __attribute__((ext_vector_type(4))) __bf16;
using f32x4  = __attribute__((ext_vector_type(4))) float;

#define MFMA16(a, b, c) __builtin_amdgcn_mfma_f32_16x16x32_bf16((a), (b), (c), 0, 0, 0)
#define WAIT_VM0() asm volatile("s_waitcnt vmcnt(0)" ::: "memory")
#define WAITBAR(N) asm volatile("s_waitcnt vmcnt(" #N ")\n\ts_barrier" ::: "memory")

__device__ __forceinline__ bf16x8 ld8(const bf16* p) { return *(const bf16x8*)p; }

// async global->LDS, 16B/lane; lds_base is wave-uniform, HW adds lane*16.
__device__ __forceinline__ void ldg_lds16(bf16* lds_base, const bf16* g) {
    __builtin_amdgcn_global_load_lds(
        (const __attribute__((address_space(1))) void*)g,
        (__attribute__((address_space(3))) void*)lds_base, 16, 0, 0);
}

__device__ __forceinline__ float fast_exp2(float x) {
#if __has_builtin(__builtin_amdgcn_exp2f)
    return __builtin_amdgcn_exp2f(x);
#else
    return exp2f(x);
#endif
}

// ---------------------------------------------------------------------------
// Merged prep: z=0..3 transpose+convert W*; z=4 convert x -> bf16.
// ---------------------------------------------------------------------------
__global__ __launch_bounds__(256) void prep_kernel(
    const float* __restrict__ x, const float* __restrict__ Wq,
    const float* __restrict__ Wk, const float* __restrict__ Wv,
    const float* __restrict__ Wo, bf16* __restrict__ xb,
    bf16* __restrict__ WtBase) {
    const int z = blockIdx.z;
    const int tid = threadIdx.x;
    if (z == 4) {
        int id = blockIdx.y * 32 + blockIdx.x;      // 0..1023
#pragma unroll
        for (int k = 0; k < 4; ++k) {
            int i = id * 4096 + k * 1024 + tid * 4;
            float4 v = *(const float4*)&x[i];
            bf16x4 o = { (bf16)v.x, (bf16)v.y, (bf16)v.z, (bf16)v.w };
            *(bf16x4*)&xb[i] = o;
        }
        return;
    }
    __shared__ float tile[32][33];
    const float* W = (z == 0) ? Wq : (z == 1) ? Wk : (z == 2) ? Wv : Wo;
    bf16* Wt = WtBase + (size_t)z * 1024 * 1024;
    const int tx = tid & 31, ty = tid >> 5;          // 32 x 8
    const int x0 = blockIdx.x * 32, y0 = blockIdx.y * 32;
#pragma unroll
    for (int i = 0; i < 4; ++i)
        tile[ty + i * 8][tx] = W[(size_t)(y0 + ty + i * 8) * 1024 + x0 + tx];
    __syncthreads();
#pragma unroll
    for (int i = 0; i < 4; ++i)
        Wt[(size_t)(x0 + ty + i * 8) * 1024 + y0 + tx] = (bf16)tile[tx][ty + i * 8];
}

// ---------------------------------------------------------------------------
// 128x128 GEMM core, async double-buffered (R6 exact).
// ---------------------------------------------------------------------------
__device__ __forceinline__ void gemm_stage(const bf16* __restrict__ src, int r0,
                                           int k0, bf16* dst, int w, int lane) {
#pragma unroll
    for (int c = 0; c < 2; ++c) {
        int flat = (w * 2 + c) * 64 + lane;
        int row = flat >> 2, cc = flat & 3;
        int gk = (cc ^ ((row >> 1) & 3)) * 8;
        ldg_lds16(dst + (size_t)(w * 2 + c) * 512,
                  src + (size_t)(r0 + row) * 1024 + k0 + gk);
    }
}

__device__ __forceinline__ void gemm_core_128(const bf16* __restrict__ A,
                                              const bf16* __restrict__ Bt,
                                              int m0, int n0,
                                              bf16* As, bf16* Bs,   // each 2*4096
                                              f32x4 (&acc)[4][4]) {
    const int tid = threadIdx.x, lane = tid & 63, w = tid >> 6;
    const int lo = lane & 15, quad = lane >> 4;
    const int wm = w >> 1, wn = w & 1;

    gemm_stage(A,  m0, 0, As, w, lane);
    gemm_stage(Bt, n0, 0, Bs, w, lane);
    WAIT_VM0();
    __syncthreads();

    for (int it = 0; it < 32; ++it) {
        const int buf = it & 1;
        if (it + 1 < 32) {
            gemm_stage(A,  m0, (it + 1) * 32, As + (buf ^ 1) * 4096, w, lane);
            gemm_stage(Bt, n0, (it + 1) * 32, Bs + (buf ^ 1) * 4096, w, lane);
        }
        const bf16* Ab = As + buf * 4096;
        const bf16* Bb = Bs + buf * 4096;
        bf16x8 af[4], bq[4];
#pragma unroll
        for (int t = 0; t < 4; ++t) {
            int r = wm * 64 + t * 16 + lo;
            af[t] = ld8(&Ab[r * 32 + ((quad ^ ((r >> 1) & 3)) * 8)]);
        }
#pragma unroll
        for (int t = 0; t < 4; ++t) {
            int r = wn * 64 + t * 16 + lo;
            bq[t] = ld8(&Bb[r * 32 + ((quad ^ ((r >> 1) & 3)) * 8)]);
        }
#pragma unroll
        for (int mt = 0; mt < 4; ++mt)
#pragma unroll
            for (int nt = 0; nt < 4; ++nt)
                acc[mt][nt] = MFMA16(af[mt], bq[nt], acc[mt][nt]);
        WAIT_VM0();
        __syncthreads();
    }
}

// Fused QKV projection. z=0 -> Q (scaled log2e/8), z=1 -> K, z=2 -> V
// transposed [B][H][Hd][S_perm] via LDS-transpose epilogue; the s coordinate
// is permuted within each 32-key group: col' keeps attn's PV slot mapping
// slot = quad*8 + T*4 + o  <->  key = T*16 + quad*4 + o.
__global__ __launch_bounds__(256, 3) void qkv_gemm_kernel(
    const bf16* __restrict__ Xb, const bf16* __restrict__ Wts,
    const float* __restrict__ bq, const float* __restrict__ bk,
    const float* __restrict__ bv,
    bf16* __restrict__ Qo, bf16* __restrict__ Ko, bf16* __restrict__ Vto) {
    __shared__ bf16 Smem[4 * 4096];
    bf16* As = Smem;
    bf16* Bs = Smem + 2 * 4096;
    const int z = blockIdx.z;
    const bf16*  Bt   = Wts + (size_t)z * 1024 * 1024;
    const float* bias = (z == 0) ? bq : (z == 1) ? bk : bv;
    const int m0 = blockIdx.y * 128, n0 = blockIdx.x * 128;

    f32x4 acc[4][4] = {};
    gemm_core_128(Xb, Bt, m0, n0, As, Bs, acc);

    const int tid = threadIdx.x;
    const int lane = tid & 63, w = tid >> 6;
    const int lo = lane & 15, quad = lane >> 4;
    const int wm = w >> 1, wn = w & 1;
    const float QSCALE = 0.125f * 1.44269504088896f;  // 1/sqrt(64) * log2(e)

    if (z == 2) {
        // ---- V: transpose via LDS (two 128n x 64m half-tiles, stride 68) ----
        bf16* T = Smem;                      // 128*68 = 8704 elems
        const int b = m0 >> 11;
        const int s_base = m0 & 2047;
#pragma unroll
        for (int half = 0; half < 2; ++half) {
            __syncthreads();
            if (wm == half) {
#pragma unroll
                for (int nt = 0; nt < 4; ++nt)
#pragma unroll
                    for (int mt = 0; mt < 4; ++mt)
#pragma unroll
                        for (int r = 0; r < 4; ++r) {
                            int nn = wn * 64 + nt * 16 + lo;
                            int mm = mt * 16 + quad * 4 + r;
                            T[nn * 68 + mm] = (bf16)(acc[mt][nt][r] + bias[n0 + nn]);
                        }
            }
            __syncthreads();
#pragma unroll
            for (int p = 0; p < 8; ++p) {
                int pos = p * 1024 + tid * 4;
                int row = pos >> 6, col = pos & 63;
                int n = n0 + row, h = n >> 6, hd = n & 63;
                // permute key within its 32-group: slot = q4*8 + T16*4 + o
                int colp = (col & 32) | (((col >> 2) & 3) << 3)
                         | (((col >> 4) & 1) << 2) | (col & 3);
                bf16x4 v = *(const bf16x4*)&T[row * 68 + col];
                *(bf16x4*)&Vto[((size_t)((b * 16 + h) * 64 + hd) << 11)
                               + s_base + half * 64 + colp] = v;
            }
        }
    } else {
#pragma unroll
        for (int mt = 0; mt < 4; ++mt)
#pragma unroll
            for (int nt = 0; nt < 4; ++nt)
#pragma unroll
                for (int r = 0; r < 4; ++r) {
                    int m = m0 + wm * 64 + mt * 16 + quad * 4 + r;
                    int n = n0 + wn * 64 + nt * 16 + lo;
                    float v = acc[mt][nt][r] + bias[n];
                    int b = m >> 11, s = m & 2047, h = n >> 6, hd = n & 63;
                    if (z == 0)
                        Qo[((size_t)((b * 16 + h) * 2048 + s) << 6) + hd] = (bf16)(v * QSCALE);
                    else
                        Ko[((size_t)((b * 16 + h) * 2048 + s) << 6) + hd] = (bf16)v;
                }
    }
}

// ---------------------------------------------------------------------------
// Output projection, 64x128 tiles (512 blocks = 2/CU), double-buffered (R6).
// ---------------------------------------------------------------------------
__global__ __launch_bounds__(256, 2) void out_gemm_kernel(
    const bf16* __restrict__ A, const bf16* __restrict__ Bt,
    const float* __restrict__ bo, float* __restrict__ Co) {
    __shared__ bf16 As[2 * 2048];
    __shared__ bf16 Bs[2 * 4096];
    const int tid = threadIdx.x, lane = tid & 63, w = tid >> 6;
    const int lo = lane & 15, quad = lane >> 4;
    const int wm = w >> 1, wn = w & 1;
    const int m0 = blockIdx.y * 64, n0 = blockIdx.x * 128;

    auto stageA = [&](int k0, bf16* dst) {
        int flat = w * 64 + lane;
        int row = flat >> 2, cc = flat & 3;
        int gk = (cc ^ ((row >> 1) & 3)) * 8;
        ldg_lds16(dst + (size_t)w * 512, A + (size_t)(m0 + row) * 1024 + k0 + gk);
    };
    auto stageB = [&](int k0, bf16* dst) {
#pragma unroll
        for (int c = 0; c < 2; ++c) {
            int flat = (w * 2 + c) * 64 + lane;
            int row = flat >> 2, cc = flat & 3;
            int gk = (cc ^ ((row >> 1) & 3)) * 8;
            ldg_lds16(dst + (size_t)(w * 2 + c) * 512,
                      Bt + (size_t)(n0 + row) * 1024 + k0 + gk);
        }
    };

    f32x4 acc[2][4] = {};
    stageA(0, As);
    stageB(0, Bs);
    WAIT_VM0();
    __syncthreads();

    for (int it = 0; it < 32; ++it) {
        const int buf = it & 1;
        if (it + 1 < 32) {
            stageA((it + 1) * 32, As + (buf ^ 1) * 2048);
            stageB((it + 1) * 32, Bs + (buf ^ 1) * 4096);
        }
        const bf16* Ab = As + buf * 2048;
        const bf16* Bb = Bs + buf * 4096;
        bf16x8 af[2], bq[4];
#pragma unroll
        for (int t = 0; t < 2; ++t) {
            int r = wm * 32 + t * 16 + lo;
            af[t] = ld8(&Ab[r * 32 + ((quad ^ ((r >> 1) & 3)) * 8)]);
        }
#pragma unroll
        for (int t = 0; t < 4; ++t) {
            int r = wn * 64 + t * 16 + lo;
            bq[t] = ld8(&Bb[r * 32 + ((quad ^ ((r >> 1) & 3)) * 8)]);
        }
#pragma unroll
        for (int mt = 0; mt < 2; ++mt)
#pragma unroll
            for (int nt = 0; nt < 4; ++nt)
                acc[mt][nt] = MFMA16(af[mt], bq[nt], acc[mt][nt]);
        WAIT_VM0();
        __syncthreads();
    }

#pragma unroll
    for (int mt = 0; mt < 2; ++mt)
#pragma unroll
        for (int nt = 0; nt < 4; ++nt)
#pragma unroll
            for (int r = 0; r < 4; ++r) {
                int m = m0 + wm * 32 + mt * 16 + quad * 4 + r;
                int n = n0 + wn * 64 + nt * 16 + lo;
                Co[(size_t)m * 1024 + n] = acc[mt][nt][r] + bo[n];
            }
}

// ---------------------------------------------------------------------------
// Flash attention (R10 structure + hoisted-zero S init): software-pipelined
// S^T formulation. Grid 512 x 256 (4 waves, 2 blk/CU). Block = 128 q-rows of
// one (b,h); each wave owns 32 q. 64-key chunks, K+V 4-deep LDS (64KB),
// staged 2 ahead, 4 ldg_lds/wave/chunk, counted WAITBAR(4). Per iteration
// (one scheduling region, no internal barrier):
//   exp(S_i) [VALU] || S_{i+1}=K*Q^T [MFMA+LDS] || O+=P_i*V_i [MFMA+LDS]
// ---------------------------------------------------------------------------
__global__ __launch_bounds__(256, 2) void attn_kernel(
    const bf16* __restrict__ Q, const bf16* __restrict__ K,
    const bf16* __restrict__ Vt, bf16* __restrict__ AO) {
    __shared__ bf16 Ks[4][64 * 64];
    __shared__ bf16 Vs[4][64 * 64];
    const int tid = threadIdx.x, w = tid >> 6, lane = tid & 63;
    const int lo = lane & 15, quad = lane >> 4;
    const int blk = blockIdx.x;
    const int bh = (blk & 7) | ((blk >> 7) << 3);  // same-head -> same XCD
    const int qb = (blk >> 3) & 15;
    const int q0 = qb * 128 + w * 32;

    const bf16* Qb = Q + ((size_t)bh * 2048 + q0) * 64;
    const bf16* Kb = K + (size_t)bh * 2048 * 64;
    const bf16* Vb = Vt + (size_t)bh * 64 * 2048;

    // Q B-fragments: n-row = qt*16+lo, k = ks*32+quad*8
    bf16x8 qa[2][2];
#pragma unroll
    for (int qt = 0; qt < 2; ++qt)
#pragma unroll
        for (int ks = 0; ks < 2; ++ks)
            qa[qt][ks] = ld8(&Qb[(qt * 16 + lo) * 64 + ks * 32 + quad * 8]);

    f32x4 O[2][4] = {};
    float l_acc[2] = { 0.f, 0.f };
    const f32x4 ZERO = { 0.f, 0.f, 0.f, 0.f };   // hoisted C-operand

    // stage one 64-key K+V chunk (4 ldg_lds/wave); swizzle s(row)=row&7 both.
    auto stage = [&](int s0, int buf) {
#pragma unroll
        for (int c = 0; c < 2; ++c) {
            int flat = (w * 2 + c) * 64 + lane;
            int row = flat >> 3, cc = flat & 7;
            int g = (cc ^ (row & 7)) * 8;
            ldg_lds16(&Ks[buf][(w * 2 + c) * 512], &Kb[(size_t)(s0 + row) * 64 + g]);
            ldg_lds16(&Vs[buf][(w * 2 + c) * 512], &Vb[(size_t)row * 2048 + s0 + g]);
        }
    };

    const int swz = lo & 7;  // read-side swizzle for rows t*16+lo

    // ---- S^T = K * Q^T from Ks[nb] : 4 key m-tiles x 2 q n-tiles x 2 k ----
    auto qk = [&](int nb, f32x4 (&S)[2][4]) {
        const bf16* Kt = &Ks[nb][0];
#pragma unroll
        for (int t = 0; t < 4; ++t) {
            int r = t * 16 + lo;
            bf16x8 kf0 = ld8(&Kt[r * 64 + ((quad ^ swz) * 8)]);
            S[0][t] = MFMA16(kf0, qa[0][0], ZERO);
            S[1][t] = MFMA16(kf0, qa[1][0], ZERO);
            bf16x8 kf1 = ld8(&Kt[r * 64 + (((quad + 4) ^ swz) * 8)]);
            S[0][t] = MFMA16(kf1, qa[0][1], S[0][t]);
            S[1][t] = MFMA16(kf1, qa[1][1], S[1][t]);
        }
    };

    // ---- exp(Sin) -> pa (PV A-frags, keys slot-permuted) + l_acc ----
    auto expP = [&](f32x4 (&Sin)[2][4], bf16x8 (&pa)[2][2]) {
#pragma unroll
        for (int qt = 0; qt < 2; ++qt)
#pragma unroll
            for (int kc = 0; kc < 2; ++kc) {
                float e0 = fast_exp2(Sin[qt][2 * kc][0]);
                float e1 = fast_exp2(Sin[qt][2 * kc][1]);
                float e2 = fast_exp2(Sin[qt][2 * kc][2]);
                float e3 = fast_exp2(Sin[qt][2 * kc][3]);
                float e4 = fast_exp2(Sin[qt][2 * kc + 1][0]);
                float e5 = fast_exp2(Sin[qt][2 * kc + 1][1]);
                float e6 = fast_exp2(Sin[qt][2 * kc + 1][2]);
                float e7 = fast_exp2(Sin[qt][2 * kc + 1][3]);
                l_acc[qt] += ((e0 + e1) + (e2 + e3)) + ((e4 + e5) + (e6 + e7));
                pa[qt][kc] = bf16x8{ (bf16)e0, (bf16)e1, (bf16)e2, (bf16)e3,
                                     (bf16)e4, (bf16)e5, (bf16)e6, (bf16)e7 };
            }
    };

    // ---- PV from Vs[cb] ----
    auto pv = [&](int cb, bf16x8 (&pa)[2][2]) {
        const bf16* Vl = &Vs[cb][0];
#pragma unroll
        for (int kc = 0; kc < 2; ++kc)
#pragma unroll
            for (int nt = 0; nt < 4; ++nt) {
                int r = nt * 16 + lo;
                bf16x8 vf = ld8(&Vl[r * 64 + ((((kc * 4 + quad) ^ swz)) * 8)]);
                O[0][nt] = MFMA16(pa[0][kc], vf, O[0][nt]);
                O[1][nt] = MFMA16(pa[1][kc], vf, O[1][nt]);
            }
    };

    // step i: exp(S_i) || S_{i+1}=qk || O+=P_i*V_i  (one region, no barrier)
    auto step = [&](f32x4 (&Sin)[2][4], f32x4 (&Sout)[2][4], int cb, int nb) {
        bf16x8 pa[2][2];
        expP(Sin, pa);
        qk(nb, Sout);
        pv(cb, pa);
    };

    stage(0, 0);
    stage(64, 1);
    WAITBAR(4);                     // chunk0 ready; chunk1 in flight

    f32x4 Sa[2][4], Sb[2][4];
    qk(0, Sa);

    for (int it = 0; it < 30; it += 2) {
        stage((it + 2) * 64, (it + 2) & 3);
        WAITBAR(4);                 // chunk it+1 ready
        step(Sa, Sb, it & 3, (it + 1) & 3);
        stage((it + 3) * 64, (it + 3) & 3);
        WAITBAR(4);                 // chunk it+2 ready
        step(Sb, Sa, (it + 1) & 3, (it + 2) & 3);
    }
    WAITBAR(0);                     // chunk 31 ready
    step(Sa, Sb, 2, 3);             // exp(S30) || qk(31) || PV(30)
    {                               // tail: exp(S31) + PV(31)
        bf16x8 pa[2][2];
        expP(Sb, pa);
        pv(3, pa);
    }

    // ---- epilogue: l lives at q=lo; redistribute to C-rows via shfl ----
    const int bb = bh >> 4, h = bh & 15;
#pragma unroll
    for (int qt = 0; qt < 2; ++qt) {
        float lt = l_acc[qt];
        lt += __shfl_xor(lt, 16, 64);
        lt += __shfl_xor(lt, 32, 64);   // total l for q = qt*16 + lo
        const size_t outbase = ((size_t)(bb * 2048 + q0 + qt * 16)) * 1024 + h * 64;
#pragma unroll
        for (int r = 0; r < 4; ++r) {
            float rl = 1.0f / __shfl(lt, quad * 4 + r, 64);
            size_t rowoff = outbase + (size_t)(quad * 4 + r) * 1024;
#pragma unroll
            for (int nt = 0; nt < 4; ++nt)
                AO[rowoff + nt * 16 + lo] = (bf16)(O[qt][nt][r] * rl);
        }
    }
}

// ---------------------------------------------------------------------------
extern "C" void kernel_launch(void* const* d_in, const int* in_sizes, int n_in,
                              void* d_out, int out_size, void* d_ws, size_t ws_size,
                              hipStream_t stream) {
    const float* x  = (const float*)d_in[0];
    const float* Wq = (const float*)d_in[1];
    const float* bq = (const float*)d_in[2];
    const float* Wk = (const float*)d_in[3];
    const float* bk = (const float*)d_in[4];
    const float* Wv = (const float*)d_in[5];
    const float* bv = (const float*)d_in[6];
    const float* Wo = (const float*)d_in[7];
    const float* bo = (const float*)d_in[8];
    float* out = (float*)d_out;

    bf16* wsb = (bf16*)d_ws;
    const size_t M1 = 1024u * 1024u;
    bf16* Xb  = wsb;
    bf16* AO  = wsb;            // aliases Xb (Xb dead after qkv_gemm)
    bf16* Wt  = wsb + 4 * M1;
    bf16* Qw  = wsb + 8 * M1;
    bf16* Kw  = wsb + 12 * M1;
    bf16* Vtw = wsb + 16 * M1;

    prep_kernel<<<dim3(32, 32, 5), 256, 0, stream>>>(x, Wq, Wk, Wv, Wo, Xb, Wt);
    qkv_gemm_kernel<<<dim3(8, 32, 3), 256, 0, stream>>>(Xb, Wt, bq, bk, bv, Qw, Kw, Vtw);
    attn_kernel<<<512, 256, 0, stream>>>(Qw, Kw, Vtw, AO);
    out_gemm_kernel<<<dim3(8, 64), 256, 0, stream>>>(AO, Wt + 3 * M1, bo, out);
}